// Round 1
// baseline (3270.498 us; speedup 1.0000x reference)
//
#include <hip/hip_runtime.h>
#include <math.h>

#define TPTS 200000
#define BB 2
#define NPTS (BB*TPTS)
#define GRID3 32768
#define BG 65536
#define ENC_NEG_INF ((int)0x807FFFFF)

__device__ __forceinline__ int encf(float f){ int i=__float_as_int(f); return i>=0 ? i : (i^0x7fffffff); }
__device__ __forceinline__ float decf(int i){ return __int_as_float(i>=0 ? i : (i^0x7fffffff)); }

// x[64] -> y[32]:  y = x@ws + ( relu( relu( relu(x)@w0 + b0 ) )@w1 + b1 )
__device__ __forceinline__ void resblock64(const float x[64],
    const float* __restrict__ w0, const float* __restrict__ b0,
    const float* __restrict__ w1, const float* __restrict__ b1,
    const float* __restrict__ ws, float y[32])
{
  float h[32];
#pragma unroll
  for (int j = 0; j < 32; j++) h[j] = b0[j];
#pragma unroll
  for (int k = 0; k < 64; k++) {
    float xv = fmaxf(x[k], 0.f);
#pragma unroll
    for (int j = 0; j < 32; j++) h[j] = fmaf(xv, w0[k*32+j], h[j]);
  }
#pragma unroll
  for (int j = 0; j < 32; j++) { y[j] = b1[j]; h[j] = fmaxf(h[j], 0.f); }
#pragma unroll
  for (int k = 0; k < 64; k++) {
    float xv = x[k];
#pragma unroll
    for (int j = 0; j < 32; j++) y[j] = fmaf(xv, ws[k*32+j], y[j]);
  }
#pragma unroll
  for (int k = 0; k < 32; k++) {
    float hv = h[k];
#pragma unroll
    for (int j = 0; j < 32; j++) y[j] = fmaf(hv, w1[k*32+j], y[j]);
  }
}

__global__ void k_init(int* __restrict__ cm0, int* __restrict__ cm1,
                       float* __restrict__ cnt, float* __restrict__ outp)
{
  int t = blockIdx.x*256 + threadIdx.x;
  if (t < BG*32) { cm0[t] = ENC_NEG_INF; cm1[t] = ENC_NEG_INF; outp[t] = 0.f; }
  if (t < BG) cnt[t] = 0.f;
}

__global__ void k_reinit(int* __restrict__ cm)
{
  int t = blockIdx.x*256 + threadIdx.x;
  if (t < BG*32) cm[t] = ENC_NEG_INF;
}

// pos-encode + fc_pos + resblock0; writes net (SoA [32][NPTS]), gidx, scatter-max -> cm
__global__ __launch_bounds__(256) void k_stage0(
    const float* __restrict__ p,
    const float* __restrict__ Wp, const float* __restrict__ bp,
    const float* __restrict__ w0, const float* __restrict__ b0,
    const float* __restrict__ w1, const float* __restrict__ b1,
    const float* __restrict__ ws,
    float* __restrict__ net, int* __restrict__ gbuf, int* __restrict__ cm)
{
  int t = blockIdx.x*256 + threadIdx.x;
  if (t >= NPTS) return;
  float p0 = p[3*t], p1 = p[3*t+1], p2 = p[3*t+2];

  // cell index — must match reference arithmetic exactly (true fp32 division)
  const float DEN = (float)(1.0 + 0.1 + 1e-3);
  const float HI  = (float)(1.0 - 1e-3);
  float n0 = fminf(fmaxf(p0/DEN + 0.5f, 0.f), HI);
  float n1 = fminf(fmaxf(p1/DEN + 0.5f, 0.f), HI);
  float n2 = fminf(fmaxf(p2/DEN + 0.5f, 0.f), HI);
  int c0 = (int)floorf(n0*32.f), c1 = (int)floorf(n1*32.f), c2 = (int)floorf(n2*32.f);
  int g = c0 + 32*(c1 + 32*c2) + (t >= TPTS ? GRID3 : 0);
  gbuf[t] = g;

  float x[64];
#pragma unroll
  for (int j = 0; j < 64; j++) x[j] = bp[j];

  float q0 = 2.f*p0 - 1.f, q1 = 2.f*p1 - 1.f, q2 = 2.f*p2 - 1.f;
  const float PIF = 3.14159265358979323846f;
  float u0 = q0, u1 = q1, u2 = q2;
#pragma unroll
  for (int l = 0; l < 10; l++) {
    float uu[3] = {u0, u1, u2};
#pragma unroll
    for (int d = 0; d < 3; d++) {
      // u = q*2^l is exact; reduce mod 2 exactly, then sin(pi*r), cos(pi*r)
      float r = uu[d] - 2.f*rintf(0.5f*uu[d]);
      float s, c;
      __sincosf(PIF*r, &s, &c);
      const float* wsr = Wp + (l*6 + d)*64;      // sin row
      const float* wcr = Wp + (l*6 + 3 + d)*64;  // cos row
#pragma unroll
      for (int j = 0; j < 64; j++) x[j] = fmaf(s, wsr[j], fmaf(c, wcr[j], x[j]));
    }
    u0 *= 2.f; u1 *= 2.f; u2 *= 2.f;
  }

  float y[32];
  resblock64(x, w0, b0, w1, b1, ws, y);
#pragma unroll
  for (int j = 0; j < 32; j++) net[j*NPTS + t] = y[j];
  int* cp = cm + g*32;
#pragma unroll
  for (int j = 0; j < 32; j++) atomicMax(cp + j, encf(y[j]));
}

// gather pooled max, concat, resblock i, scatter-max into cm_out (i = 1..3)
__global__ __launch_bounds__(256) void k_stage(
    float* __restrict__ net, const int* __restrict__ gbuf,
    const int* __restrict__ cm_in, int* __restrict__ cm_out,
    const float* __restrict__ w0, const float* __restrict__ b0,
    const float* __restrict__ w1, const float* __restrict__ b1,
    const float* __restrict__ ws)
{
  int t = blockIdx.x*256 + threadIdx.x;
  if (t >= NPTS) return;
  float x[64];
#pragma unroll
  for (int j = 0; j < 32; j++) x[j] = net[j*NPTS + t];
  int g = gbuf[t];
  const int4* cp4 = (const int4*)(cm_in + g*32);
#pragma unroll
  for (int q = 0; q < 8; q++) {
    int4 v = cp4[q];
    x[32 + 4*q + 0] = decf(v.x);
    x[32 + 4*q + 1] = decf(v.y);
    x[32 + 4*q + 2] = decf(v.z);
    x[32 + 4*q + 3] = decf(v.w);
  }
  float y[32];
  resblock64(x, w0, b0, w1, b1, ws, y);
#pragma unroll
  for (int j = 0; j < 32; j++) net[j*NPTS + t] = y[j];
  int* co = cm_out + g*32;
#pragma unroll
  for (int j = 0; j < 32; j++) atomicMax(co + j, encf(y[j]));
}

// gather pooled max, resblock 4, fc_c, scatter-add sums into d_out and counts
__global__ __launch_bounds__(256) void k_final(
    const float* __restrict__ net, const int* __restrict__ gbuf,
    const int* __restrict__ cm_in,
    const float* __restrict__ w0, const float* __restrict__ b0,
    const float* __restrict__ w1, const float* __restrict__ b1,
    const float* __restrict__ ws,
    const float* __restrict__ wc, const float* __restrict__ bc,
    float* __restrict__ outp, float* __restrict__ cnt)
{
  int t = blockIdx.x*256 + threadIdx.x;
  if (t >= NPTS) return;
  float x[64];
#pragma unroll
  for (int j = 0; j < 32; j++) x[j] = net[j*NPTS + t];
  int g = gbuf[t];
  const int4* cp4 = (const int4*)(cm_in + g*32);
#pragma unroll
  for (int q = 0; q < 8; q++) {
    int4 v = cp4[q];
    x[32 + 4*q + 0] = decf(v.x);
    x[32 + 4*q + 1] = decf(v.y);
    x[32 + 4*q + 2] = decf(v.z);
    x[32 + 4*q + 3] = decf(v.w);
  }
  float y[32];
  resblock64(x, w0, b0, w1, b1, ws, y);

  float c[32];
#pragma unroll
  for (int j = 0; j < 32; j++) c[j] = bc[j];
#pragma unroll
  for (int k = 0; k < 32; k++) {
    float yv = y[k];
#pragma unroll
    for (int j = 0; j < 32; j++) c[j] = fmaf(yv, wc[k*32+j], c[j]);
  }

  int b = g >> 15, cell = g & 32767;
  float* dst = outp + ((size_t)b << 20) + cell;  // b*32*32768 + ch*32768 + cell
#pragma unroll
  for (int j = 0; j < 32; j++) atomicAdd(dst + (j << 15), c[j]);
  atomicAdd(cnt + g, 1.f);
}

__global__ void k_div(float* __restrict__ outp, const float* __restrict__ cnt)
{
  int t = blockIdx.x*256 + threadIdx.x;
  if (t >= BG*32) return;
  int cell = t & 32767;
  int b = t >> 20;
  float n = cnt[(b << 15) | cell];
  outp[t] = outp[t] / fmaxf(n, 1.f);
}

extern "C" void kernel_launch(void* const* d_in, const int* in_sizes, int n_in,
                              void* d_out, int out_size, void* d_ws, size_t ws_size,
                              hipStream_t stream)
{
  const float* p   = (const float*)d_in[0];
  const float* Wp  = (const float*)d_in[1];
  const float* bp  = (const float*)d_in[2];
  const float* f0w = (const float*)d_in[3];
  const float* f0b = (const float*)d_in[4];
  const float* f1w = (const float*)d_in[5];
  const float* f1b = (const float*)d_in[6];
  const float* scw = (const float*)d_in[7];
  const float* wc  = (const float*)d_in[8];
  const float* bc  = (const float*)d_in[9];
  float* outp = (float*)d_out;

  char* wsb = (char*)d_ws;
  float* net  = (float*)wsb;                                  // NPTS*32 f32 = 51.2 MB
  int*   gbuf = (int*)(wsb + (size_t)NPTS*32*4);              // NPTS i32
  int*   cm0  = (int*)(wsb + (size_t)NPTS*33*4);              // BG*32 i32
  int*   cm1  = cm0 + (size_t)BG*32;                          // BG*32 i32
  float* cnt  = (float*)(cm1 + (size_t)BG*32);                // BG f32

  dim3 blk(256);
  dim3 gpts((NPTS + 255)/256);
  dim3 gcm((BG*32 + 255)/256);

  hipLaunchKernelGGL(k_init, gcm, blk, 0, stream, cm0, cm1, cnt, outp);
  hipLaunchKernelGGL(k_stage0, gpts, blk, 0, stream,
                     p, Wp, bp, f0w, f0b, f1w, f1b, scw, net, gbuf, cm0);
  hipLaunchKernelGGL(k_stage, gpts, blk, 0, stream,
                     net, gbuf, cm0, cm1,
                     f0w + 1*2048, f0b + 1*32, f1w + 1*1024, f1b + 1*32, scw + 1*2048);
  hipLaunchKernelGGL(k_reinit, gcm, blk, 0, stream, cm0);
  hipLaunchKernelGGL(k_stage, gpts, blk, 0, stream,
                     net, gbuf, cm1, cm0,
                     f0w + 2*2048, f0b + 2*32, f1w + 2*1024, f1b + 2*32, scw + 2*2048);
  hipLaunchKernelGGL(k_reinit, gcm, blk, 0, stream, cm1);
  hipLaunchKernelGGL(k_stage, gpts, blk, 0, stream,
                     net, gbuf, cm0, cm1,
                     f0w + 3*2048, f0b + 3*32, f1w + 3*1024, f1b + 3*32, scw + 3*2048);
  hipLaunchKernelGGL(k_final, gpts, blk, 0, stream,
                     net, gbuf, cm1,
                     f0w + 4*2048, f0b + 4*32, f1w + 4*1024, f1b + 4*32, scw + 4*2048,
                     wc, bc, outp, cnt);
  hipLaunchKernelGGL(k_div, gcm, blk, 0, stream, outp, cnt);
}

// Round 2
// 964.663 us; speedup vs baseline: 3.3903x; 3.3903x over previous
//
#include <hip/hip_runtime.h>
#include <math.h>

#define TPTS 200000
#define BB 2
#define NPTS (BB*TPTS)
#define GRID3 32768
#define BG 65536   // BB * GRID3

// x[64] -> y[32]:  y = x@ws + ( relu( relu( relu(x)@w0 + b0 ) )@w1 + b1 )
__device__ __forceinline__ void resblock64(const float x[64],
    const float* __restrict__ w0, const float* __restrict__ b0,
    const float* __restrict__ w1, const float* __restrict__ b1,
    const float* __restrict__ ws, float y[32])
{
  float h[32];
#pragma unroll
  for (int j = 0; j < 32; j++) h[j] = b0[j];
#pragma unroll
  for (int k = 0; k < 64; k++) {
    float xv = fmaxf(x[k], 0.f);
#pragma unroll
    for (int j = 0; j < 32; j++) h[j] = fmaf(xv, w0[k*32+j], h[j]);
  }
#pragma unroll
  for (int j = 0; j < 32; j++) { y[j] = b1[j]; h[j] = fmaxf(h[j], 0.f); }
#pragma unroll
  for (int k = 0; k < 64; k++) {
    float xv = x[k];
#pragma unroll
    for (int j = 0; j < 32; j++) y[j] = fmaf(xv, ws[k*32+j], y[j]);
  }
#pragma unroll
  for (int k = 0; k < 32; k++) {
    float hv = h[k];
#pragma unroll
    for (int j = 0; j < 32; j++) y[j] = fmaf(hv, w1[k*32+j], y[j]);
  }
}

// cell id: must match reference fp32 arithmetic exactly
__device__ __forceinline__ int cellof(float p0, float p1, float p2, int t)
{
  const float DEN = (float)(1.0 + 0.1 + 1e-3);
  const float HI  = (float)(1.0 - 1e-3);
  float n0 = fminf(fmaxf(p0/DEN + 0.5f, 0.f), HI);
  float n1 = fminf(fmaxf(p1/DEN + 0.5f, 0.f), HI);
  float n2 = fminf(fmaxf(p2/DEN + 0.5f, 0.f), HI);
  int c0 = (int)floorf(n0*32.f), c1 = (int)floorf(n1*32.f), c2 = (int)floorf(n2*32.f);
  return c0 + 32*(c1 + 32*c2) + (t >= TPTS ? GRID3 : 0);
}

__global__ __launch_bounds__(256) void k_hist(
    const float* __restrict__ p, int* __restrict__ gbuf, int* __restrict__ hist)
{
  int t = blockIdx.x*256 + threadIdx.x;
  if (t >= NPTS) return;
  int g = cellof(p[3*t], p[3*t+1], p[3*t+2], t);
  gbuf[t] = g;
  atomicAdd(hist + g, 1);
}

// single-block exclusive scan of hist[BG] -> start[BG+1], cursor[BG]
__global__ __launch_bounds__(1024) void k_scan(
    const int* __restrict__ hist, int* __restrict__ start, int* __restrict__ cursor)
{
  __shared__ int sums[1024];
  const int tid = threadIdx.x;
  const int base = tid * (BG/1024);           // 64 entries per thread
  int acc = 0;
#pragma unroll 4
  for (int k = 0; k < BG/1024; k++) acc += hist[base+k];
  sums[tid] = acc;
  __syncthreads();
  for (int off = 1; off < 1024; off <<= 1) {
    int v = sums[tid];
    int u = (tid >= off) ? sums[tid-off] : 0;
    __syncthreads();
    sums[tid] = v + u;
    __syncthreads();
  }
  int run = (tid > 0) ? sums[tid-1] : 0;
#pragma unroll 4
  for (int k = 0; k < BG/1024; k++) {
    start[base+k] = run; cursor[base+k] = run;
    run += hist[base+k];
  }
  if (tid == 1023) start[BG] = sums[1023];
}

// pos-encode + fc_pos + resblock0; scatter into sorted slot
__global__ __launch_bounds__(256) void k_stage0(
    const float* __restrict__ p, const int* __restrict__ gbuf,
    const float* __restrict__ Wp, const float* __restrict__ bp,
    const float* __restrict__ w0, const float* __restrict__ b0,
    const float* __restrict__ w1, const float* __restrict__ b1,
    const float* __restrict__ ws,
    int* __restrict__ cursor, float* __restrict__ net, int* __restrict__ gsort)
{
  int t = blockIdx.x*256 + threadIdx.x;
  if (t >= NPTS) return;
  float p0 = p[3*t], p1 = p[3*t+1], p2 = p[3*t+2];

  float x[64];
#pragma unroll
  for (int j = 0; j < 64; j++) x[j] = bp[j];

  float q0 = 2.f*p0 - 1.f, q1 = 2.f*p1 - 1.f, q2 = 2.f*p2 - 1.f;
  const float PIF = 3.14159265358979323846f;
  float u0 = q0, u1 = q1, u2 = q2;
#pragma unroll
  for (int l = 0; l < 10; l++) {
    float uu[3] = {u0, u1, u2};
#pragma unroll
    for (int d = 0; d < 3; d++) {
      float r = uu[d] - 2.f*rintf(0.5f*uu[d]);   // exact mod-2 reduction
      float s, c;
      __sincosf(PIF*r, &s, &c);
      const float* wsr = Wp + (l*6 + d)*64;      // sin row
      const float* wcr = Wp + (l*6 + 3 + d)*64;  // cos row
#pragma unroll
      for (int j = 0; j < 64; j++) x[j] = fmaf(s, wsr[j], fmaf(c, wcr[j], x[j]));
    }
    u0 *= 2.f; u1 *= 2.f; u2 *= 2.f;
  }

  float y[32];
  resblock64(x, w0, b0, w1, b1, ws, y);

  int g = gbuf[t];
  int slot = atomicAdd(cursor + g, 1);
  gsort[slot] = g;
  float4* dst = (float4*)(net + (size_t)slot*32);
#pragma unroll
  for (int q = 0; q < 8; q++) dst[q] = make_float4(y[4*q], y[4*q+1], y[4*q+2], y[4*q+3]);
}

// per (cell,ch) max over the cell's contiguous range
__global__ __launch_bounds__(256) void k_pool(
    const float* __restrict__ net, const int* __restrict__ start,
    float* __restrict__ pooled)
{
  int tid = blockIdx.x*256 + threadIdx.x;
  if (tid >= BG*32) return;
  int ch = tid & 31, c = tid >> 5;
  int s = start[c], e = start[c+1];
  float m = -INFINITY;
  for (int k = s; k < e; k++) m = fmaxf(m, net[(size_t)k*32 + ch]);
  pooled[tid] = m;
}

// sorted-space stage: x = [net[i], pooled[gsort[i]]]; resblock -> net[i]
__global__ __launch_bounds__(256) void k_stage(
    float* __restrict__ net, const int* __restrict__ gsort,
    const float* __restrict__ pooled,
    const float* __restrict__ w0, const float* __restrict__ b0,
    const float* __restrict__ w1, const float* __restrict__ b1,
    const float* __restrict__ ws)
{
  int i = blockIdx.x*256 + threadIdx.x;
  if (i >= NPTS) return;
  float x[64];
  const float4* np4 = (const float4*)(net + (size_t)i*32);
#pragma unroll
  for (int q = 0; q < 8; q++) {
    float4 v = np4[q];
    x[4*q] = v.x; x[4*q+1] = v.y; x[4*q+2] = v.z; x[4*q+3] = v.w;
  }
  int g = gsort[i];
  const float4* pp4 = (const float4*)(pooled + (size_t)g*32);
#pragma unroll
  for (int q = 0; q < 8; q++) {
    float4 v = pp4[q];
    x[32+4*q] = v.x; x[32+4*q+1] = v.y; x[32+4*q+2] = v.z; x[32+4*q+3] = v.w;
  }
  float y[32];
  resblock64(x, w0, b0, w1, b1, ws, y);
  float4* dst = (float4*)(net + (size_t)i*32);
#pragma unroll
  for (int q = 0; q < 8; q++) dst[q] = make_float4(y[4*q], y[4*q+1], y[4*q+2], y[4*q+3]);
}

// last stage + fc_c; overwrites net[i] with c[32]
__global__ __launch_bounds__(256) void k_final(
    float* __restrict__ net, const int* __restrict__ gsort,
    const float* __restrict__ pooled,
    const float* __restrict__ w0, const float* __restrict__ b0,
    const float* __restrict__ w1, const float* __restrict__ b1,
    const float* __restrict__ ws,
    const float* __restrict__ wc, const float* __restrict__ bc)
{
  int i = blockIdx.x*256 + threadIdx.x;
  if (i >= NPTS) return;
  float x[64];
  const float4* np4 = (const float4*)(net + (size_t)i*32);
#pragma unroll
  for (int q = 0; q < 8; q++) {
    float4 v = np4[q];
    x[4*q] = v.x; x[4*q+1] = v.y; x[4*q+2] = v.z; x[4*q+3] = v.w;
  }
  int g = gsort[i];
  const float4* pp4 = (const float4*)(pooled + (size_t)g*32);
#pragma unroll
  for (int q = 0; q < 8; q++) {
    float4 v = pp4[q];
    x[32+4*q] = v.x; x[32+4*q+1] = v.y; x[32+4*q+2] = v.z; x[32+4*q+3] = v.w;
  }
  float y[32];
  resblock64(x, w0, b0, w1, b1, ws, y);

  float c[32];
#pragma unroll
  for (int j = 0; j < 32; j++) c[j] = bc[j];
#pragma unroll
  for (int k = 0; k < 32; k++) {
    float yv = y[k];
#pragma unroll
    for (int j = 0; j < 32; j++) c[j] = fmaf(yv, wc[k*32+j], c[j]);
  }
  float4* dst = (float4*)(net + (size_t)i*32);
#pragma unroll
  for (int q = 0; q < 8; q++) dst[q] = make_float4(c[4*q], c[4*q+1], c[4*q+2], c[4*q+3]);
}

// per (cell,ch) mean over contiguous range -> out[b][ch][cell]; empty cells -> 0
__global__ __launch_bounds__(256) void k_mean(
    const float* __restrict__ net, const int* __restrict__ start,
    float* __restrict__ outp)
{
  int tid = blockIdx.x*256 + threadIdx.x;
  if (tid >= BG*32) return;
  int ch = tid & 31, c = tid >> 5;
  int s = start[c], e = start[c+1];
  float sum = 0.f;
  for (int k = s; k < e; k++) sum += net[(size_t)k*32 + ch];
  float v = (e > s) ? sum / (float)(e - s) : 0.f;
  int b = c >> 15, cell = c & 32767;
  outp[((size_t)b << 20) + ((size_t)ch << 15) + cell] = v;
}

extern "C" void kernel_launch(void* const* d_in, const int* in_sizes, int n_in,
                              void* d_out, int out_size, void* d_ws, size_t ws_size,
                              hipStream_t stream)
{
  const float* p   = (const float*)d_in[0];
  const float* Wp  = (const float*)d_in[1];
  const float* bp  = (const float*)d_in[2];
  const float* f0w = (const float*)d_in[3];
  const float* f0b = (const float*)d_in[4];
  const float* f1w = (const float*)d_in[5];
  const float* f1b = (const float*)d_in[6];
  const float* scw = (const float*)d_in[7];
  const float* wc  = (const float*)d_in[8];
  const float* bc  = (const float*)d_in[9];
  float* outp = (float*)d_out;

  char* wsb = (char*)d_ws;
  float* net    = (float*)wsb;                                   // NPTS*32 f32 = 51.2 MB
  float* pooled = net + (size_t)NPTS*32;                         // BG*32 f32  = 8.4 MB
  int*   gbuf   = (int*)(pooled + (size_t)BG*32);                // NPTS i32
  int*   gsort  = gbuf + NPTS;                                   // NPTS i32
  int*   hist   = gsort + NPTS;                                  // BG i32
  int*   start  = hist + BG;                                     // BG+1 i32
  int*   cursor = start + BG + 1;                                // BG i32

  dim3 blk(256);
  dim3 gpts((NPTS + 255)/256);
  dim3 gcell((BG*32 + 255)/256);

  hipMemsetAsync(hist, 0, (size_t)BG*4, stream);
  hipLaunchKernelGGL(k_hist, gpts, blk, 0, stream, p, gbuf, hist);
  hipLaunchKernelGGL(k_scan, dim3(1), dim3(1024), 0, stream, hist, start, cursor);
  hipLaunchKernelGGL(k_stage0, gpts, blk, 0, stream,
                     p, gbuf, Wp, bp, f0w, f0b, f1w, f1b, scw, cursor, net, gsort);
  hipLaunchKernelGGL(k_pool, gcell, blk, 0, stream, net, start, pooled);
  hipLaunchKernelGGL(k_stage, gpts, blk, 0, stream, net, gsort, pooled,
                     f0w + 1*2048, f0b + 1*32, f1w + 1*1024, f1b + 1*32, scw + 1*2048);
  hipLaunchKernelGGL(k_pool, gcell, blk, 0, stream, net, start, pooled);
  hipLaunchKernelGGL(k_stage, gpts, blk, 0, stream, net, gsort, pooled,
                     f0w + 2*2048, f0b + 2*32, f1w + 2*1024, f1b + 2*32, scw + 2*2048);
  hipLaunchKernelGGL(k_pool, gcell, blk, 0, stream, net, start, pooled);
  hipLaunchKernelGGL(k_stage, gpts, blk, 0, stream, net, gsort, pooled,
                     f0w + 3*2048, f0b + 3*32, f1w + 3*1024, f1b + 3*32, scw + 3*2048);
  hipLaunchKernelGGL(k_pool, gcell, blk, 0, stream, net, start, pooled);
  hipLaunchKernelGGL(k_final, gpts, blk, 0, stream, net, gsort, pooled,
                     f0w + 4*2048, f0b + 4*32, f1w + 4*1024, f1b + 4*32, scw + 4*2048,
                     wc, bc);
  hipLaunchKernelGGL(k_mean, gcell, blk, 0, stream, net, start, outp);
}

// Round 3
// 798.427 us; speedup vs baseline: 4.0962x; 1.2082x over previous
//
#include <hip/hip_runtime.h>
#include <math.h>

#define TPTS 200000
#define BB 2
#define NPTS (BB*TPTS)
#define GRID3 32768
#define BG 65536   // BB * GRID3

// cell id: must match reference fp32 arithmetic exactly
__device__ __forceinline__ int cellof(float p0, float p1, float p2, int t)
{
  const float DEN = (float)(1.0 + 0.1 + 1e-3);
  const float HI  = (float)(1.0 - 1e-3);
  float n0 = fminf(fmaxf(p0/DEN + 0.5f, 0.f), HI);
  float n1 = fminf(fmaxf(p1/DEN + 0.5f, 0.f), HI);
  float n2 = fminf(fmaxf(p2/DEN + 0.5f, 0.f), HI);
  int c0 = (int)floorf(n0*32.f), c1 = (int)floorf(n1*32.f), c2 = (int)floorf(n2*32.f);
  return c0 + 32*(c1 + 32*c2) + (t >= TPTS ? GRID3 : 0);
}

__global__ __launch_bounds__(256) void k_hist(
    const float* __restrict__ p, int* __restrict__ gbuf, int* __restrict__ hist)
{
  int t = blockIdx.x*256 + threadIdx.x;
  if (t >= NPTS) return;
  int g = cellof(p[3*t], p[3*t+1], p[3*t+2], t);
  gbuf[t] = g;
  atomicAdd(hist + g, 1);
}

// single-block exclusive scan of hist[BG] -> start[BG+1], cursor[BG]
__global__ __launch_bounds__(1024) void k_scan(
    const int* __restrict__ hist, int* __restrict__ start, int* __restrict__ cursor)
{
  __shared__ int sums[1024];
  const int tid = threadIdx.x;
  const int base = tid * (BG/1024);
  int acc = 0;
#pragma unroll 4
  for (int k = 0; k < BG/1024; k++) acc += hist[base+k];
  sums[tid] = acc;
  __syncthreads();
  for (int off = 1; off < 1024; off <<= 1) {
    int v = sums[tid];
    int u = (tid >= off) ? sums[tid-off] : 0;
    __syncthreads();
    sums[tid] = v + u;
    __syncthreads();
  }
  int run = (tid > 0) ? sums[tid-1] : 0;
#pragma unroll 4
  for (int k = 0; k < BG/1024; k++) {
    start[base+k] = run; cursor[base+k] = run;
    run += hist[base+k];
  }
  if (tid == 1023) start[BG] = sums[1023];
}

// permute raw coords into sorted order (12 B scatter per point, done once)
__global__ __launch_bounds__(256) void k_scatter(
    const float* __restrict__ p, const int* __restrict__ gbuf,
    int* __restrict__ cursor, float* __restrict__ p_sorted, int* __restrict__ gsort)
{
  int t = blockIdx.x*256 + threadIdx.x;
  if (t >= NPTS) return;
  int g = gbuf[t];
  int slot = atomicAdd(cursor + g, 1);
  gsort[slot] = g;
  p_sorted[3*slot]   = p[3*t];
  p_sorted[3*slot+1] = p[3*t+1];
  p_sorted[3*slot+2] = p[3*t+2];
}

// posenc + fc_pos -> xbuf (SoA [64][NPTS]), sorted order, rolled l-loop (small code)
__global__ __launch_bounds__(256) void k_stage0(
    const float* __restrict__ ps,
    const float* __restrict__ Wp, const float* __restrict__ bp,
    float* __restrict__ xbuf)
{
  int i = blockIdx.x*256 + threadIdx.x;
  if (i >= NPTS) return;
  float p0 = ps[3*i], p1 = ps[3*i+1], p2 = ps[3*i+2];

  float x[64];
#pragma unroll
  for (int j = 0; j < 64; j++) x[j] = bp[j];

  float u0 = 2.f*p0 - 1.f, u1 = 2.f*p1 - 1.f, u2 = 2.f*p2 - 1.f;
  const float PIF = 3.14159265358979323846f;
#pragma unroll 1
  for (int l = 0; l < 10; l++) {
    float uu[3] = {u0, u1, u2};
#pragma unroll
    for (int d = 0; d < 3; d++) {
      float r = uu[d] - 2.f*rintf(0.5f*uu[d]);   // exact mod-2 reduction
      float s, c;
      __sincosf(PIF*r, &s, &c);
      const float* wsr = Wp + (l*6 + d)*64;      // sin row
      const float* wcr = Wp + (l*6 + 3 + d)*64;  // cos row
#pragma unroll
      for (int j = 0; j < 64; j++) x[j] = fmaf(s, wsr[j], fmaf(c, wcr[j], x[j]));
    }
    u0 *= 2.f; u1 *= 2.f; u2 *= 2.f;
  }
#pragma unroll
  for (int j = 0; j < 64; j++) xbuf[(size_t)j*NPTS + i] = x[j];
}

// resblock0: K=64 streamed from xbuf, h/y in regs, rolled k-loop -> net SoA [32][NPTS]
__global__ __launch_bounds__(256) void k_res0(
    const float* __restrict__ xbuf,
    const float* __restrict__ w0, const float* __restrict__ b0,
    const float* __restrict__ w1, const float* __restrict__ b1,
    const float* __restrict__ ws,
    float* __restrict__ net)
{
  int i = blockIdx.x*256 + threadIdx.x;
  if (i >= NPTS) return;
  float h[32], y[32];
#pragma unroll
  for (int j = 0; j < 32; j++) { h[j] = b0[j]; y[j] = b1[j]; }
#pragma unroll 2
  for (int k = 0; k < 64; k++) {
    float xv = xbuf[(size_t)k*NPTS + i];
    float xr = fmaxf(xv, 0.f);
    const float* w0r = w0 + k*32;
    const float* wsr = ws + k*32;
#pragma unroll
    for (int j = 0; j < 32; j++) {
      h[j] = fmaf(xr, w0r[j], h[j]);
      y[j] = fmaf(xv, wsr[j], y[j]);
    }
  }
#pragma unroll
  for (int j = 0; j < 32; j++) h[j] = fmaxf(h[j], 0.f);
#pragma unroll
  for (int k = 0; k < 32; k++) {
    float hv = h[k];
#pragma unroll
    for (int j = 0; j < 32; j++) y[j] = fmaf(hv, w1[k*32+j], y[j]);
  }
#pragma unroll
  for (int j = 0; j < 32; j++) net[(size_t)j*NPTS + i] = y[j];
}

// middle stages: own 32 ch from net (coalesced) + pooled 32 ch (broadcast-ish)
__global__ __launch_bounds__(256) void k_stage(
    float* __restrict__ net, const int* __restrict__ gsort,
    const float* __restrict__ pooled,
    const float* __restrict__ w0, const float* __restrict__ b0,
    const float* __restrict__ w1, const float* __restrict__ b1,
    const float* __restrict__ ws)
{
  int i = blockIdx.x*256 + threadIdx.x;
  if (i >= NPTS) return;
  int g = gsort[i];
  float h[32], y[32];
#pragma unroll
  for (int j = 0; j < 32; j++) { h[j] = b0[j]; y[j] = b1[j]; }
#pragma unroll 2
  for (int k = 0; k < 32; k++) {
    float xv = net[(size_t)k*NPTS + i];
    float xr = fmaxf(xv, 0.f);
    const float* w0r = w0 + k*32;
    const float* wsr = ws + k*32;
#pragma unroll
    for (int j = 0; j < 32; j++) {
      h[j] = fmaf(xr, w0r[j], h[j]);
      y[j] = fmaf(xv, wsr[j], y[j]);
    }
  }
#pragma unroll 2
  for (int k = 0; k < 32; k++) {
    float xv = pooled[(size_t)k*BG + g];
    float xr = fmaxf(xv, 0.f);
    const float* w0r = w0 + (32+k)*32;
    const float* wsr = ws + (32+k)*32;
#pragma unroll
    for (int j = 0; j < 32; j++) {
      h[j] = fmaf(xr, w0r[j], h[j]);
      y[j] = fmaf(xv, wsr[j], y[j]);
    }
  }
#pragma unroll
  for (int j = 0; j < 32; j++) h[j] = fmaxf(h[j], 0.f);
#pragma unroll
  for (int k = 0; k < 32; k++) {
    float hv = h[k];
#pragma unroll
    for (int j = 0; j < 32; j++) y[j] = fmaf(hv, w1[k*32+j], y[j]);
  }
#pragma unroll
  for (int j = 0; j < 32; j++) net[(size_t)j*NPTS + i] = y[j];
}

// last stage + fc_c -> net holds c[32] per point
__global__ __launch_bounds__(256) void k_final(
    float* __restrict__ net, const int* __restrict__ gsort,
    const float* __restrict__ pooled,
    const float* __restrict__ w0, const float* __restrict__ b0,
    const float* __restrict__ w1, const float* __restrict__ b1,
    const float* __restrict__ ws,
    const float* __restrict__ wc, const float* __restrict__ bc)
{
  int i = blockIdx.x*256 + threadIdx.x;
  if (i >= NPTS) return;
  int g = gsort[i];
  float h[32], y[32];
#pragma unroll
  for (int j = 0; j < 32; j++) { h[j] = b0[j]; y[j] = b1[j]; }
#pragma unroll 2
  for (int k = 0; k < 32; k++) {
    float xv = net[(size_t)k*NPTS + i];
    float xr = fmaxf(xv, 0.f);
    const float* w0r = w0 + k*32;
    const float* wsr = ws + k*32;
#pragma unroll
    for (int j = 0; j < 32; j++) {
      h[j] = fmaf(xr, w0r[j], h[j]);
      y[j] = fmaf(xv, wsr[j], y[j]);
    }
  }
#pragma unroll 2
  for (int k = 0; k < 32; k++) {
    float xv = pooled[(size_t)k*BG + g];
    float xr = fmaxf(xv, 0.f);
    const float* w0r = w0 + (32+k)*32;
    const float* wsr = ws + (32+k)*32;
#pragma unroll
    for (int j = 0; j < 32; j++) {
      h[j] = fmaf(xr, w0r[j], h[j]);
      y[j] = fmaf(xv, wsr[j], y[j]);
    }
  }
#pragma unroll
  for (int j = 0; j < 32; j++) h[j] = fmaxf(h[j], 0.f);
#pragma unroll
  for (int k = 0; k < 32; k++) {
    float hv = h[k];
#pragma unroll
    for (int j = 0; j < 32; j++) y[j] = fmaf(hv, w1[k*32+j], y[j]);
  }
  float c[32];
#pragma unroll
  for (int j = 0; j < 32; j++) c[j] = bc[j];
#pragma unroll
  for (int k = 0; k < 32; k++) {
    float yv = y[k];
#pragma unroll
    for (int j = 0; j < 32; j++) c[j] = fmaf(yv, wc[k*32+j], c[j]);
  }
#pragma unroll
  for (int j = 0; j < 32; j++) net[(size_t)j*NPTS + i] = c[j];
}

// per (ch, cell) max over the cell's contiguous range; cell fastest -> coalesced
__global__ __launch_bounds__(256) void k_pool(
    const float* __restrict__ net, const int* __restrict__ start,
    float* __restrict__ pooled)
{
  int tid = blockIdx.x*256 + threadIdx.x;   // [0, 32*BG)
  int c = tid & (BG-1), ch = tid >> 16;
  int s = start[c], e = start[c+1];
  const float* base = net + (size_t)ch*NPTS;
  float m = -INFINITY;
  for (int k = s; k < e; k++) m = fmaxf(m, base[k]);
  pooled[(size_t)ch*BG + c] = m;
}

// per (ch, cell) mean -> out[b][ch][cell]; empty cells -> 0
__global__ __launch_bounds__(256) void k_mean(
    const float* __restrict__ net, const int* __restrict__ start,
    float* __restrict__ outp)
{
  int tid = blockIdx.x*256 + threadIdx.x;
  int c = tid & (BG-1), ch = tid >> 16;
  int s = start[c], e = start[c+1];
  const float* base = net + (size_t)ch*NPTS;
  float sum = 0.f;
  for (int k = s; k < e; k++) sum += base[k];
  float v = (e > s) ? sum / (float)(e - s) : 0.f;
  int b = c >> 15, cell = c & 32767;
  outp[((size_t)b << 20) + ((size_t)ch << 15) + cell] = v;
}

extern "C" void kernel_launch(void* const* d_in, const int* in_sizes, int n_in,
                              void* d_out, int out_size, void* d_ws, size_t ws_size,
                              hipStream_t stream)
{
  const float* p   = (const float*)d_in[0];
  const float* Wp  = (const float*)d_in[1];
  const float* bp  = (const float*)d_in[2];
  const float* f0w = (const float*)d_in[3];
  const float* f0b = (const float*)d_in[4];
  const float* f1w = (const float*)d_in[5];
  const float* f1b = (const float*)d_in[6];
  const float* scw = (const float*)d_in[7];
  const float* wc  = (const float*)d_in[8];
  const float* bc  = (const float*)d_in[9];
  float* outp = (float*)d_out;

  char* wsb = (char*)d_ws;
  float* net      = (float*)wsb;                         // NPTS*32 f32 = 51.2 MB
  int*   gbuf     = (int*)(net + (size_t)NPTS*32);       // NPTS
  int*   gsort    = gbuf + NPTS;                         // NPTS
  int*   hist     = gsort + NPTS;                        // BG
  int*   start    = hist + BG;                           // BG+1
  int*   cursor   = start + BG + 1;                      // BG
  float* p_sorted = (float*)(cursor + BG);               // NPTS*3
  float* xbuf     = p_sorted + (size_t)NPTS*3;           // NPTS*64 f32 = 102.4 MB
  float* pooled   = xbuf;                                // aliases xbuf (xbuf dead after k_res0)

  dim3 blk(256);
  dim3 gpts((NPTS + 255)/256);
  dim3 gcell((BG*32)/256);

  hipMemsetAsync(hist, 0, (size_t)BG*4, stream);
  hipLaunchKernelGGL(k_hist, gpts, blk, 0, stream, p, gbuf, hist);
  hipLaunchKernelGGL(k_scan, dim3(1), dim3(1024), 0, stream, hist, start, cursor);
  hipLaunchKernelGGL(k_scatter, gpts, blk, 0, stream, p, gbuf, cursor, p_sorted, gsort);
  hipLaunchKernelGGL(k_stage0, gpts, blk, 0, stream, p_sorted, Wp, bp, xbuf);
  hipLaunchKernelGGL(k_res0, gpts, blk, 0, stream,
                     xbuf, f0w, f0b, f1w, f1b, scw, net);
  hipLaunchKernelGGL(k_pool, gcell, blk, 0, stream, net, start, pooled);
  hipLaunchKernelGGL(k_stage, gpts, blk, 0, stream, net, gsort, pooled,
                     f0w + 1*2048, f0b + 1*32, f1w + 1*1024, f1b + 1*32, scw + 1*2048);
  hipLaunchKernelGGL(k_pool, gcell, blk, 0, stream, net, start, pooled);
  hipLaunchKernelGGL(k_stage, gpts, blk, 0, stream, net, gsort, pooled,
                     f0w + 2*2048, f0b + 2*32, f1w + 2*1024, f1b + 2*32, scw + 2*2048);
  hipLaunchKernelGGL(k_pool, gcell, blk, 0, stream, net, start, pooled);
  hipLaunchKernelGGL(k_stage, gpts, blk, 0, stream, net, gsort, pooled,
                     f0w + 3*2048, f0b + 3*32, f1w + 3*1024, f1b + 3*32, scw + 3*2048);
  hipLaunchKernelGGL(k_pool, gcell, blk, 0, stream, net, start, pooled);
  hipLaunchKernelGGL(k_final, gpts, blk, 0, stream, net, gsort, pooled,
                     f0w + 4*2048, f0b + 4*32, f1w + 4*1024, f1b + 4*32, scw + 4*2048,
                     wc, bc);
  hipLaunchKernelGGL(k_mean, gcell, blk, 0, stream, net, start, outp);
}